// Round 1
// baseline (49.605 us; speedup 1.0000x reference)
//
#include <hip/hip_runtime.h>
#include <cstdint>
#include <cstddef>

#define MAXG 128

struct GateList { int n; int code[MAXG]; };

// ---------------- host-side: reproduce numpy legacy RandomState(42) ----------------
namespace {

struct MT19937 {
  uint32_t mt[624]; int mti;
  void seed(uint32_t s) {
    mt[0] = s;
    for (int i = 1; i < 624; i++)
      mt[i] = 1812433253u * (mt[i-1] ^ (mt[i-1] >> 30)) + (uint32_t)i;
    mti = 624;
  }
  uint32_t next() {
    if (mti >= 624) {
      for (int i = 0; i < 624; i++) {
        uint32_t y = (mt[i] & 0x80000000u) | (mt[(i+1) % 624] & 0x7fffffffu);
        mt[i] = mt[(i+397) % 624] ^ (y >> 1) ^ ((y & 1u) ? 2567483615u : 0u);
      }
      mti = 0;
    }
    uint32_t y = mt[mti++];
    y ^= y >> 11; y ^= (y << 7) & 2636928640u; y ^= (y << 15) & 4022730752u; y ^= y >> 18;
    return y;
  }
  // legacy rk_double: two 32-bit draws
  double rdouble() {
    uint32_t a = next() >> 5, b = next() >> 6;
    return ((double)a * 67108864.0 + (double)b) / 9007199254740992.0;
  }
  // legacy randint: masked rejection on 32-bit draws (range fits 32-bit)
  uint32_t masked32(uint32_t rng, uint32_t mask) {
    uint32_t v; do { v = next() & mask; } while (v > rng); return v;
  }
  // random_interval (used by shuffle): inclusive max, 32-bit draws
  uint32_t interval(uint32_t mx) {
    if (!mx) return 0;
    uint32_t mask = mx;
    mask |= mask >> 1; mask |= mask >> 2; mask |= mask >> 4; mask |= mask >> 8; mask |= mask >> 16;
    uint32_t v; do { v = next() & mask; } while (v > mx); return v;
  }
};

// gate code: bits[1:0] = kind (0=RX,1=RY,2=RZ,3=CNOT)
//   R:    bits[5:2] = wire bit mask (8>>wire), bits[10:6] = weight index l*8+i
//   CNOT: bits[5:2] = control bit mask,        bits[9:6]  = target bit mask
GateList build_gates() {
  GateList gl; gl.n = 0;
  MT19937 rng; rng.seed(42);
  for (int l = 0; l < 4; l++) {
    int i = 0;
    while (i < 8) {
      if (rng.rdouble() > 0.3) {
        int g = (int)rng.masked32(2, 3);   // randint(3)
        int w = (int)rng.masked32(3, 3);   // randint(4)
        int widx = l * 8 + i;
        if (gl.n < MAXG) gl.code[gl.n++] = g | ((8 >> w) << 2) | (widx << 6);
        i++;
      } else {
        // choice(4,2,replace=False) == permutation(4)[:2]; shuffle i=3,2,1
        int perm[4] = {0, 1, 2, 3};
        for (int ii = 3; ii >= 1; ii--) {
          int j = (int)rng.interval((uint32_t)ii);
          int tmp = perm[ii]; perm[ii] = perm[j]; perm[j] = tmp;
        }
        int cw = perm[0], tw = perm[1];
        if (gl.n < MAXG) gl.code[gl.n++] = 3 | ((8 >> cw) << 2) | ((8 >> tw) << 6);
      }
    }
  }
  return gl;
}

} // namespace

// ---------------- kernel 1: build the fixed 16x16 unitary from weights ----------------
__global__ __launch_bounds__(256) void build_u(const float* __restrict__ w,
                                               float* __restrict__ ws, GateList gl) {
  __shared__ float Ur[16][16], Ui[16][16];
  int t = threadIdx.x;
  int k = t >> 4, col = t & 15;
  Ur[k][col] = (k == col) ? 1.0f : 0.0f;
  Ui[k][col] = 0.0f;
  __syncthreads();
  for (int g = 0; g < gl.n; g++) {
    int code = gl.code[g];
    int kind = code & 3;
    float nr, ni;
    if (kind == 3) {                       // CNOT
      int cbit = (code >> 2) & 15, tbit = (code >> 6) & 15;
      int src = (k & cbit) ? (k ^ tbit) : k;
      nr = Ur[src][col]; ni = Ui[src][col];
    } else {
      int bit  = (code >> 2) & 15;
      int widx = (code >> 6) & 31;
      float h = 0.5f * w[widx];
      float ch = cosf(h), sh = sinf(h);
      int partner = k ^ bit;
      float osr = Ur[k][col], osi = Ui[k][col];
      float opr = Ur[partner][col], opi = Ui[partner][col];
      if (kind == 0) {                     // RX: new = c*self - i*s*partner
        nr = ch * osr + sh * opi; ni = ch * osi - sh * opr;
      } else if (kind == 1) {              // RY: [[c,-s],[s,c]]
        if (k & bit) { nr = sh * opr + ch * osr; ni = sh * opi + ch * osi; }
        else         { nr = ch * osr - sh * opr; ni = ch * osi - sh * opi; }
      } else {                             // RZ: diag(c-is, c+is)
        if (k & bit) { nr = ch * osr - sh * osi; ni = ch * osi + sh * osr; }
        else         { nr = ch * osr + sh * osi; ni = ch * osi - sh * osr; }
      }
    }
    __syncthreads();
    Ur[k][col] = nr; Ui[k][col] = ni;
    __syncthreads();
  }
  // interleaved (re,im) pairs: float2 index = k*16 + i
  ws[(k * 16 + col) * 2]     = Ur[k][col];
  ws[(k * 16 + col) * 2 + 1] = Ui[k][col];
}

// ---------------- kernel 2: per-patch amplitudes + expectation values ----------------
// grid: 512 blocks x 256 thr; thread = (b, jj, q) with kk = 4q+p, p=0..3
__global__ __launch_bounds__(256) void qonv_main(const float* __restrict__ img,
                                                 const float* __restrict__ uws,
                                                 float* __restrict__ out) {
  __shared__ float4 U4[128];               // U4[k*8+i2] = (re_{2i2}, im_{2i2}, re_{2i2+1}, im_{2i2+1})
  int t = threadIdx.x;
  if (t < 128) U4[t] = ((const float4*)uws)[t];
  __syncthreads();

  unsigned tid = blockIdx.x * 256u + (unsigned)t;
  int q  = tid & 31;                       // 0..31 -> kk base 4q
  int jj = (tid >> 5) & 127;               // patch row
  int b  = tid >> 12;                      // batch

  const float* row0 = img + ((size_t)(b * 512 + 2 * jj) * 512) * 3 + 24 * (size_t)q;
  const float* row1 = row0 + 512 * 3;
  float r0[24], r1[24];
  #pragma unroll
  for (int v = 0; v < 6; v++) {
    float4 x0 = ((const float4*)row0)[v];
    float4 x1 = ((const float4*)row1)[v];
    r0[4*v] = x0.x; r0[4*v+1] = x0.y; r0[4*v+2] = x0.z; r0[4*v+3] = x0.w;
    r1[4*v] = x1.x; r1[4*v+1] = x1.y; r1[4*v+2] = x1.z; r1[4*v+3] = x1.w;
  }

  const float inv3 = 1.0f / 3.0f;
  float s16[4][16];
  #pragma unroll
  for (int p = 0; p < 4; p++) {
    float a0 = (r0[6*p]   + r0[6*p+1] + r0[6*p+2]) * inv3;
    float a1 = (r0[6*p+3] + r0[6*p+4] + r0[6*p+5]) * inv3;
    float a2 = (r1[6*p]   + r1[6*p+1] + r1[6*p+2]) * inv3;
    float a3 = (r1[6*p+3] + r1[6*p+4] + r1[6*p+5]) * inv3;
    float c0, s0, c1, s1, c2, s2, c3, s3;
    __sincosf(0.5f * a0, &s0, &c0);
    __sincosf(0.5f * a1, &s1, &c1);
    __sincosf(0.5f * a2, &s2, &c2);
    __sincosf(0.5f * a3, &s3, &c3);
    float A[4] = {c0*c1, c0*s1, s0*c1, s0*s1};
    float B[4] = {c2*c3, c2*s3, s2*c3, s2*s3};
    #pragma unroll
    for (int hi = 0; hi < 4; hi++)
      #pragma unroll
      for (int lo = 0; lo < 4; lo++)
        s16[p][hi * 4 + lo] = A[hi] * B[lo];
  }

  float acc[4][4];                          // [p][ch]
  #pragma unroll
  for (int p = 0; p < 4; p++)
    #pragma unroll
    for (int c = 0; c < 4; c++) acc[p][c] = 0.0f;

  #pragma unroll
  for (int k = 0; k < 16; k++) {
    float ar[4] = {0,0,0,0}, ai[4] = {0,0,0,0};
    #pragma unroll
    for (int i2 = 0; i2 < 8; i2++) {
      float4 u = U4[k * 8 + i2];
      #pragma unroll
      for (int p = 0; p < 4; p++) {
        ar[p] += u.x * s16[p][2*i2] + u.z * s16[p][2*i2+1];
        ai[p] += u.y * s16[p][2*i2] + u.w * s16[p][2*i2+1];
      }
    }
    #pragma unroll
    for (int p = 0; p < 4; p++) {
      float pk = ar[p]*ar[p] + ai[p]*ai[p];
      #pragma unroll
      for (int ch = 0; ch < 4; ch++) {
        if (k & (8 >> ch)) acc[p][ch] -= pk; else acc[p][ch] += pk;
      }
    }
  }

  size_t obase = ((size_t)(b * 256 + jj) * 256 + 4 * (size_t)q) * 4;
  #pragma unroll
  for (int p = 0; p < 4; p++)
    ((float4*)(out + obase))[p] = make_float4(acc[p][0], acc[p][1], acc[p][2], acc[p][3]);
}

extern "C" void kernel_launch(void* const* d_in, const int* in_sizes, int n_in,
                              void* d_out, int out_size, void* d_ws, size_t ws_size,
                              hipStream_t stream) {
  const float* img = (const float*)d_in[0];
  const float* wts = (const float*)d_in[1];
  float* out = (float*)d_out;

  GateList gl = build_gates();             // deterministic, ~50 gates, host-side

  hipMemsetAsync(d_out, 0, (size_t)out_size * sizeof(float), stream);
  build_u<<<1, 256, 0, stream>>>(wts, (float*)d_ws, gl);
  qonv_main<<<512, 256, 0, stream>>>(img, (const float*)d_ws, out);
}

// Round 2
// 39.330 us; speedup vs baseline: 1.2612x; 1.2612x over previous
//
#include <hip/hip_runtime.h>
#include <cstdint>
#include <cstddef>

#define MAXG 128

struct GateList { int n; int code[MAXG]; };

// ---------------- host-side: reproduce numpy legacy RandomState(42) ----------------
namespace {

struct MT19937 {
  uint32_t mt[624]; int mti;
  void seed(uint32_t s) {
    mt[0] = s;
    for (int i = 1; i < 624; i++)
      mt[i] = 1812433253u * (mt[i-1] ^ (mt[i-1] >> 30)) + (uint32_t)i;
    mti = 624;
  }
  uint32_t next() {
    if (mti >= 624) {
      for (int i = 0; i < 624; i++) {
        uint32_t y = (mt[i] & 0x80000000u) | (mt[(i+1) % 624] & 0x7fffffffu);
        mt[i] = mt[(i+397) % 624] ^ (y >> 1) ^ ((y & 1u) ? 2567483615u : 0u);
      }
      mti = 0;
    }
    uint32_t y = mt[mti++];
    y ^= y >> 11; y ^= (y << 7) & 2636928640u; y ^= (y << 15) & 4022730752u; y ^= y >> 18;
    return y;
  }
  double rdouble() {
    uint32_t a = next() >> 5, b = next() >> 6;
    return ((double)a * 67108864.0 + (double)b) / 9007199254740992.0;
  }
  uint32_t masked32(uint32_t rng, uint32_t mask) {
    uint32_t v; do { v = next() & mask; } while (v > rng); return v;
  }
  uint32_t interval(uint32_t mx) {
    if (!mx) return 0;
    uint32_t mask = mx;
    mask |= mask >> 1; mask |= mask >> 2; mask |= mask >> 4; mask |= mask >> 8; mask |= mask >> 16;
    uint32_t v; do { v = next() & mask; } while (v > mx); return v;
  }
};

// gate code: bits[1:0] = kind (0=RX,1=RY,2=RZ,3=CNOT)
//   R:    bits[5:2] = wire bit mask (8>>wire), bits[10:6] = weight index l*8+i
//   CNOT: bits[5:2] = control bit mask,        bits[9:6]  = target bit mask
GateList build_gates() {
  GateList gl; gl.n = 0;
  MT19937 rng; rng.seed(42);
  for (int l = 0; l < 4; l++) {
    int i = 0;
    while (i < 8) {
      if (rng.rdouble() > 0.3) {
        int g = (int)rng.masked32(2, 3);   // randint(3)
        int w = (int)rng.masked32(3, 3);   // randint(4)
        int widx = l * 8 + i;
        if (gl.n < MAXG) gl.code[gl.n++] = g | ((8 >> w) << 2) | (widx << 6);
        i++;
      } else {
        int perm[4] = {0, 1, 2, 3};
        for (int ii = 3; ii >= 1; ii--) {
          int j = (int)rng.interval((uint32_t)ii);
          int tmp = perm[ii]; perm[ii] = perm[j]; perm[j] = tmp;
        }
        int cw = perm[0], tw = perm[1];
        if (gl.n < MAXG) gl.code[gl.n++] = 3 | ((8 >> cw) << 2) | ((8 >> tw) << 6);
      }
    }
  }
  return gl;
}

} // namespace

// ---------------- kernel 1: build the fixed 16x16 unitary from weights ----------------
__global__ __launch_bounds__(256) void build_u(const float* __restrict__ w,
                                               float* __restrict__ ws, GateList gl) {
  __shared__ float Ur[16][16], Ui[16][16];
  int t = threadIdx.x;
  int k = t >> 4, col = t & 15;
  Ur[k][col] = (k == col) ? 1.0f : 0.0f;
  Ui[k][col] = 0.0f;
  __syncthreads();
  for (int g = 0; g < gl.n; g++) {
    int code = gl.code[g];
    int kind = code & 3;
    float nr, ni;
    if (kind == 3) {                       // CNOT
      int cbit = (code >> 2) & 15, tbit = (code >> 6) & 15;
      int src = (k & cbit) ? (k ^ tbit) : k;
      nr = Ur[src][col]; ni = Ui[src][col];
    } else {
      int bit  = (code >> 2) & 15;
      int widx = (code >> 6) & 31;
      float h = 0.5f * w[widx];
      float ch = cosf(h), sh = sinf(h);
      int partner = k ^ bit;
      float osr = Ur[k][col], osi = Ui[k][col];
      float opr = Ur[partner][col], opi = Ui[partner][col];
      if (kind == 0) {                     // RX
        nr = ch * osr + sh * opi; ni = ch * osi - sh * opr;
      } else if (kind == 1) {              // RY
        if (k & bit) { nr = sh * opr + ch * osr; ni = sh * opi + ch * osi; }
        else         { nr = ch * osr - sh * opr; ni = ch * osi - sh * opi; }
      } else {                             // RZ
        if (k & bit) { nr = ch * osr - sh * osi; ni = ch * osi + sh * osr; }
        else         { nr = ch * osr + sh * osi; ni = ch * osi - sh * osr; }
      }
    }
    __syncthreads();
    Ur[k][col] = nr; Ui[k][col] = ni;
    __syncthreads();
  }
  ws[(k * 16 + col) * 2]     = Ur[k][col];
  ws[(k * 16 + col) * 2 + 1] = Ui[k][col];
}

// ---------------- kernel 2: patches + zero-fill of the whole output ----------------
// thread = (b, jj, q), q=0..63; patches kk = q and 64+q; also writes all zeros so no
// separate memset is needed. grid: 1024 blocks x 256 thr.
__global__ __launch_bounds__(256) void qonv_main(const float* __restrict__ img,
                                                 const float* __restrict__ uws,
                                                 float* __restrict__ out) {
  __shared__ float4 U4[128];               // U4[k*8+i2] = (re_{2i2}, im_{2i2}, re_{2i2+1}, im_{2i2+1})
  int t = threadIdx.x;
  if (t < 128) U4[t] = ((const float4*)uws)[t];
  __syncthreads();

  unsigned tid = blockIdx.x * 256u + (unsigned)t;
  int q  = tid & 63;                       // lane-dense patch index
  int jj = (tid >> 6) & 127;               // patch row
  int b  = tid >> 13;                      // batch

  const float* row0 = img + (size_t)(b * 512 + 2 * jj) * 1536;
  const float* row1 = row0 + 1536;

  const float inv3 = 1.0f / 3.0f;
  float s16[2][16];
  #pragma unroll
  for (int p = 0; p < 2; p++) {
    int off = 384 * p + 6 * q;             // floats; 8B-aligned (q even stride)
    float2 x0 = *(const float2*)(row0 + off);
    float2 x1 = *(const float2*)(row0 + off + 2);
    float2 x2 = *(const float2*)(row0 + off + 4);
    float2 y0 = *(const float2*)(row1 + off);
    float2 y1 = *(const float2*)(row1 + off + 2);
    float2 y2 = *(const float2*)(row1 + off + 4);
    float a0 = (x0.x + x0.y + x1.x) * inv3;   // (row0, col0)
    float a1 = (x1.y + x2.x + x2.y) * inv3;   // (row0, col1)
    float a2 = (y0.x + y0.y + y1.x) * inv3;   // (row1, col0)
    float a3 = (y1.y + y2.x + y2.y) * inv3;   // (row1, col1)
    float c0, s0, c1, s1, c2, s2, c3, s3;
    __sincosf(0.5f * a0, &s0, &c0);
    __sincosf(0.5f * a1, &s1, &c1);
    __sincosf(0.5f * a2, &s2, &c2);
    __sincosf(0.5f * a3, &s3, &c3);
    float A[4] = {c0*c1, c0*s1, s0*c1, s0*s1};
    float B[4] = {c2*c3, c2*s3, s2*c3, s2*s3};
    #pragma unroll
    for (int hi = 0; hi < 4; hi++)
      #pragma unroll
      for (int lo = 0; lo < 4; lo++)
        s16[p][hi * 4 + lo] = A[hi] * B[lo];
  }

  float acc[2][4];
  #pragma unroll
  for (int p = 0; p < 2; p++)
    #pragma unroll
    for (int c = 0; c < 4; c++) acc[p][c] = 0.0f;

  #pragma unroll
  for (int k = 0; k < 16; k++) {
    float ar[2] = {0, 0}, ai[2] = {0, 0};
    #pragma unroll
    for (int i2 = 0; i2 < 8; i2++) {
      float4 u = U4[k * 8 + i2];
      #pragma unroll
      for (int p = 0; p < 2; p++) {
        ar[p] += u.x * s16[p][2*i2] + u.z * s16[p][2*i2+1];
        ai[p] += u.y * s16[p][2*i2] + u.w * s16[p][2*i2+1];
      }
    }
    #pragma unroll
    for (int p = 0; p < 2; p++) {
      float pk = ar[p]*ar[p] + ai[p]*ai[p];
      #pragma unroll
      for (int ch = 0; ch < 4; ch++) {
        if (k & (8 >> ch)) acc[p][ch] -= pk; else acc[p][ch] += pk;
      }
    }
  }

  float4* o = (float4*)out;                // one float4 = 4 channels of one (b,r,c)
  size_t rowA = ((size_t)b * 256 + jj) * 256;          // computed row
  size_t rowB = ((size_t)b * 256 + 128 + jj) * 256;    // mirrored zero row
  const float4 z4 = make_float4(0.f, 0.f, 0.f, 0.f);
  o[rowA + q]       = make_float4(acc[0][0], acc[0][1], acc[0][2], acc[0][3]);
  o[rowA + 64 + q]  = make_float4(acc[1][0], acc[1][1], acc[1][2], acc[1][3]);
  o[rowA + 128 + q] = z4;
  o[rowA + 192 + q] = z4;
  o[rowB + q]       = z4;
  o[rowB + 64 + q]  = z4;
  o[rowB + 128 + q] = z4;
  o[rowB + 192 + q] = z4;
}

extern "C" void kernel_launch(void* const* d_in, const int* in_sizes, int n_in,
                              void* d_out, int out_size, void* d_ws, size_t ws_size,
                              hipStream_t stream) {
  const float* img = (const float*)d_in[0];
  const float* wts = (const float*)d_in[1];
  float* out = (float*)d_out;

  GateList gl = build_gates();             // deterministic, host-side

  build_u<<<1, 256, 0, stream>>>(wts, (float*)d_ws, gl);
  qonv_main<<<1024, 256, 0, stream>>>(img, (const float*)d_ws, out);
}